// Round 9
// baseline (613.806 us; speedup 1.0000x reference)
//
#include <hip/hip_runtime.h>
#include <stdint.h>

#define NQ 8192
#define NS 16384
#define DIM 512
#define NC 64
#define MARGIN 0.01f
#define CAND_CAP (1 << 20)     // 1M global candidates (16 MB)
#define LCAP 512               // per-block-tile LDS candidate cap (overflow -> global path)

#define BM 128
#define BN 128
#define BK 32
#define SSPLIT 16
#define SCHUNK (NS / SSPLIT)     // 1024
#define NTILES (SCHUNK / BN)     // 8
#define KSTEPS (DIM / BK)        // 16
#define TOTKS (NTILES * KSTEPS)  // 128 K-steps per block

typedef unsigned short ushort;
typedef __attribute__((ext_vector_type(8))) short bf16x8;
typedef __attribute__((ext_vector_type(4))) float f32x4;

// ---------- helpers ----------
__device__ __forceinline__ uint32_t fkey(float f) {
  uint32_t u = __float_as_uint(f);
  return (u & 0x80000000u) ? ~u : (u | 0x80000000u);
}
__device__ __forceinline__ float unfkey(uint32_t k) {
  return __uint_as_float((k & 0x80000000u) ? (k & 0x7FFFFFFFu) : ~k);
}
__device__ __forceinline__ ushort f2bf_rne(float f) {
  uint32_t u = __float_as_uint(f);
  return (ushort)((u + 0x7fffu + ((u >> 16) & 1u)) >> 16);
}
__device__ __forceinline__ void gload_lds16(const void* g, void* lds) {
  __builtin_amdgcn_global_load_lds(
      (const __attribute__((address_space(1))) uint32_t*)g,
      (__attribute__((address_space(3))) uint32_t*)lds, 16, 0, 0);
}

// ---------- pre-pass: row-normalize -> bf16 + rnorm scale ----------
__global__ void norm_bf16_kernel(const float* __restrict__ X,
                                 ushort* __restrict__ Xbf, float* __restrict__ rX,
                                 int nrows) {
  int w = threadIdx.x >> 6, l = threadIdx.x & 63;
  int row = blockIdx.x * 4 + w;
  if (row >= nrows) return;
  const float4* x = (const float4*)(X + (size_t)row * DIM);
  float4 v0 = x[l], v1 = x[l + 64];
  float s = v0.x*v0.x + v0.y*v0.y + v0.z*v0.z + v0.w*v0.w
          + v1.x*v1.x + v1.y*v1.y + v1.z*v1.z + v1.w*v1.w;
  #pragma unroll
  for (int off = 32; off; off >>= 1) s += __shfl_xor(s, off);
  float r = rsqrtf(fmaxf(s, 1e-12f));
  if (l == 0) rX[row] = r;
  size_t base = (size_t)row * DIM + 4 * l;
  *(ushort4*)&Xbf[base] = make_ushort4(f2bf_rne(v0.x*r), f2bf_rne(v0.y*r),
                                       f2bf_rne(v0.z*r), f2bf_rne(v0.w*r));
  *(ushort4*)&Xbf[base + 256] = make_ushort4(f2bf_rne(v1.x*r), f2bf_rne(v1.y*r),
                                             f2bf_rne(v1.z*r), f2bf_rne(v1.w*r));
}

// labels from one-hot + zero result/candidate state (must re-init every call)
__global__ void label_init_kernel(const float* __restrict__ oh, int* __restrict__ lab,
                                  unsigned long long* __restrict__ packedE,
                                  uint32_t* __restrict__ packedA, int* __restrict__ cnt) {
  int i = blockIdx.x * 256 + threadIdx.x;
  if (i == 0) *cnt = 0;
  if (i < NQ) { packedE[i] = 0ull; packedA[i] = 0u; }
  if (i < NS) {
    const float* row = oh + (size_t)i * NC;
    int l = 0;
    #pragma unroll
    for (int j = 0; j < NC; ++j) l = (row[j] > 0.5f) ? j : l;
    lab[i] = l;
  }
}

// ---------- pass 1: 128x128 BK=32 bf16 GEMM (round-2 structure) + margin emission ----
// 32 KB tile LDS -> 3 blocks/CU (m97 regime); one __syncthreads per K-step; compiler
// schedules all waits. 64-B rows with Z4 granule swizzle phys = g ^ (row>>2 & 3):
// fragment reads land 2 lanes/bank-quad (free); staging pre-swizzles the source.
__global__ __launch_bounds__(256) void gemm_margin_kernel(
    const ushort* __restrict__ Qbf, const ushort* __restrict__ Sbf,
    uint32_t* __restrict__ packedA, int4* __restrict__ cand, int* __restrict__ cnt)
{
  __shared__ ushort At[2][BM * BK];    // 16 KB
  __shared__ ushort Bt[2][BN * BK];    // 16 KB
  __shared__ float merged[BM][2];
  __shared__ float runmax[BM];
  __shared__ int4 lbuf[LCAP];          // 8 KB
  __shared__ int lcnt, lbase;

  const int tid = threadIdx.x;
  const int w = tid >> 6, l = tid & 63;
  const int wr = w >> 1, wcn = w & 1;           // 2 (M) x 2 (N) wave grid
  const int c = l & 15, g = l >> 4;

  // T1: XCD swizzle (1024 blocks, bijective). XCD x owns s-chunks {2x,2x+1} (2 MB, L2-fit).
  const int flat = blockIdx.x;
  const int nf = (flat & 7) * 128 + (flat >> 3);
  const int sbq = nf >> 6, qb = nf & 63;        // 16 s-chunks x 64 q-panels
  const int qbase = qb * BM, sbase = sbq * SCHUNK;

  // staging: one gload16 covers 16 rows x 64 B per wave (4 lanes/row, 16 B each)
  const int lrow = l >> 2;                               // 0..15
  const int lslot = ((l & 3) ^ ((l >> 4) & 3)) * 16;     // pre-swizzled src granule
  const char* srcA0 = (const char*)Qbf + (size_t)(qbase + w * 16 + lrow) * 1024 + lslot;
  const char* srcB0 = (const char*)Sbf + (size_t)(sbase + w * 16 + lrow) * 1024 + lslot;
  const int ldst0 = (w * 16) * 64;                       // wave-uniform dest (bytes)

  // STAGE(buf, n): 4 gload16/thread. k-block = (n&15)*64 B; B adds t-tile offset.
  #define STAGE(buf, n) do {                                                      \
    const size_t kb_ = (size_t)((n) & (KSTEPS - 1)) * 64;                         \
    const size_t tb_ = (size_t)((n) >> 4) * (BN * 1024);                          \
    gload_lds16(srcA0 + kb_,         (char*)&At[(buf)][0] + ldst0);               \
    gload_lds16(srcA0 + kb_ + 65536, (char*)&At[(buf)][0] + ldst0 + 4096);        \
    gload_lds16(srcB0 + tb_ + kb_,         (char*)&Bt[(buf)][0] + ldst0);         \
    gload_lds16(srcB0 + tb_ + kb_ + 65536, (char*)&Bt[(buf)][0] + ldst0 + 4096);  \
  } while (0)

  // fragment reads: row = base16 + c, granule g -> byte row*64 + (g^(c>>2))*16
  const int slot = (g ^ (c >> 2)) * 16;
  const int aoff = (wr * 64 + c) * 64 + slot;
  const int boff = (wcn * 64 + c) * 64 + slot;

  float rm = -2.0f;                              // running chunk max (tid < 128)
  if (tid == 0) lcnt = 0;

  // prologue: stage K-step 0 into buf 0
  STAGE(0, 0);
  __syncthreads();

  for (int t = 0; t < NTILES; ++t) {
    f32x4 acc[4][4];
    #pragma unroll
    for (int m = 0; m < 4; ++m)
      #pragma unroll
      for (int n = 0; n < 4; ++n) acc[m][n] = (f32x4)0.0f;

    for (int k = 0; k < KSTEPS; ++k) {
      const int n = t * KSTEPS + k;
      const int cur = n & 1;
      if (n + 1 < TOTKS) STAGE(cur ^ 1, n + 1);   // prefetch: full K-step to land

      const char* Ac = (const char*)&At[cur][0];
      const char* Bc = (const char*)&Bt[cur][0];
      bf16x8 a[4], b[4];
      #pragma unroll
      for (int m = 0; m < 4; ++m) a[m] = *(const bf16x8*)(Ac + aoff + m * 1024);
      #pragma unroll
      for (int j = 0; j < 4; ++j) b[j] = *(const bf16x8*)(Bc + boff + j * 1024);

      #pragma unroll
      for (int m = 0; m < 4; ++m)
        #pragma unroll
        for (int j = 0; j < 4; ++j)
          acc[m][j] = __builtin_amdgcn_mfma_f32_16x16x32_bf16(a[m], b[j], acc[m][j], 0, 0, 0);

      // single barrier per K-step; compiler emits the vmcnt/lgkm drain it needs.
      // 3 blocks/CU (m97 regime) absorb the drain via cross-block overlap (m114).
      __syncthreads();
    }

    // ---- epilogue: rowmax merge -> runmax -> two-level candidate emission ----
    // C/D: col = wcn*64 + j*16 + c ; row = wr*64 + m*16 + g*4 + r
    #pragma unroll
    for (int m = 0; m < 4; ++m)
      #pragma unroll
      for (int r = 0; r < 4; ++r) {
        float v = acc[m][0][r];
        #pragma unroll
        for (int j = 1; j < 4; ++j) v = fmaxf(v, acc[m][j][r]);
        #pragma unroll
        for (int off = 1; off < 16; off <<= 1) v = fmaxf(v, __shfl_xor(v, off));
        if (c == 0) merged[wr * 64 + m * 16 + g * 4 + r][wcn] = v;
      }
    __syncthreads();
    if (tid < BM) {
      rm = fmaxf(rm, fmaxf(merged[tid][0], merged[tid][1]));
      runmax[tid] = rm;
    }
    __syncthreads();
    {
      const int sb = sbase + t * BN + wcn * 64 + c;
      #pragma unroll
      for (int m = 0; m < 4; ++m)
        #pragma unroll
        for (int r = 0; r < 4; ++r) {
          const int row = wr * 64 + m * 16 + g * 4 + r;
          const float thr = runmax[row] - MARGIN;
          #pragma unroll
          for (int j = 0; j < 4; ++j) {
            float v = acc[m][j][r];
            if (v >= thr) {
              int s = atomicAdd(&lcnt, 1);     // LDS atomic: block-local
              if (s < LCAP) lbuf[s] = make_int4(qbase + row, sb + j * 16, __float_as_int(v), 0);
              else {                            // overflow: direct global (correctness)
                int gi = atomicAdd(cnt, 1);
                if (gi < CAND_CAP) cand[gi] = make_int4(qbase + row, sb + j * 16, __float_as_int(v), 0);
              }
            }
          }
        }
    }
    __syncthreads();
    if (tid == 0) {                             // ONE global atomic per block-tile
      int take = lcnt < LCAP ? lcnt : LCAP;
      lbase = atomicAdd(cnt, take);
      lcnt = take;
    }
    __syncthreads();
    for (int i = tid; i < lcnt; i += 256) {
      int gi = lbase + i;
      if (gi < CAND_CAP) cand[gi] = lbuf[i];
    }
    __syncthreads();
    if (tid == 0) lcnt = 0;
    __syncthreads();   // reset visible before next tile's emission
  }

  if (tid < BM) atomicMax(&packedA[qbase + tid], fkey(rm));

  #undef STAGE
}

// ---------- pass 2: exact fp32 rescore of filtered candidates ----------
__global__ void rescore_kernel(const float* __restrict__ Q, const float* __restrict__ S,
                               const float* __restrict__ rq, const float* __restrict__ rs,
                               const uint32_t* __restrict__ packedA,
                               const int4* __restrict__ cand, const int* __restrict__ cnt,
                               unsigned long long* __restrict__ packedE) {
  const int nw = (gridDim.x * blockDim.x) >> 6;
  const int wid = (blockIdx.x * blockDim.x + threadIdx.x) >> 6;
  const int l = threadIdx.x & 63;
  int n = *cnt; if (n > CAND_CAP) n = CAND_CAP;
  for (int ci = wid; ci < n; ci += nw) {
    int4 cd = cand[ci];
    float maxA = unfkey(packedA[cd.x]);
    float apx = __int_as_float(cd.z);
    if (apx < maxA - MARGIN) continue;     // provably not the winner
    const float4* qp = (const float4*)(Q + (size_t)cd.x * DIM);
    const float4* sp = (const float4*)(S + (size_t)cd.y * DIM);
    float4 a0 = qp[l], b0 = sp[l], a1 = qp[l + 64], b1 = sp[l + 64];
    float d = a0.x*b0.x + a0.y*b0.y + a0.z*b0.z + a0.w*b0.w
            + a1.x*b1.x + a1.y*b1.y + a1.z*b1.z + a1.w*b1.w;
    #pragma unroll
    for (int off = 32; off; off >>= 1) d += __shfl_xor(d, off);
    if (l == 0) {
      float ex = d * rq[cd.x] * rs[cd.y];
      unsigned long long p =
          ((unsigned long long)fkey(ex) << 32) | (uint32_t)(~(uint32_t)cd.y);
      atomicMax(&packedE[cd.x], p);
    }
  }
}

__global__ void finalize_kernel(const unsigned long long* __restrict__ packedE,
                                const int* __restrict__ lab, float* __restrict__ out) {
  int gid = blockIdx.x * 256 + threadIdx.x;
  if (gid >= NQ * NC) return;
  int q = gid >> 6, cl = gid & 63;
  unsigned long long p = packedE[q];
  if (p == 0ull) { out[gid] = 0.0f; return; }   // safety: never expected
  uint32_t n = ~(uint32_t)p;
  float v = unfkey((uint32_t)(p >> 32));
  out[gid] = (cl == lab[n]) ? v : 0.0f;
}

// ---------- launch ----------
extern "C" void kernel_launch(void* const* d_in, const int* in_sizes, int n_in,
                              void* d_out, int out_size, void* d_ws, size_t ws_size,
                              hipStream_t stream) {
  const float* Q  = (const float*)d_in[0];   // [8192, 512]
  const float* S  = (const float*)d_in[1];   // [16384, 512]
  const float* OH = (const float*)d_in[2];   // [16384, 64]
  float* out = (float*)d_out;                // [8192, 64]

  char* ws = (char*)d_ws;
  int* lab                    = (int*)(ws);                             //  64 KB
  unsigned long long* packedE = (unsigned long long*)(ws + (1 << 16));  //  64 KB
  uint32_t* packedA           = (uint32_t*)(ws + (2 << 16));            //  32 KB
  int* cnt                    = (int*)(ws + (3 << 16));                 //   4 KB
  float* rq                   = (float*)(ws + 200704);                  //  32 KB
  float* rs                   = (float*)(ws + 233472);                  //  64 KB
  ushort* Qbf                 = (ushort*)(ws + 299008);                 //   8 MB
  ushort* Sbf                 = (ushort*)(ws + 299008 + 8388608);       //  16 MB
  int4* cand                  = (int4*)(ws + 299008 + 8388608 + 16777216); // 16 MB

  norm_bf16_kernel<<<NQ / 4, 256, 0, stream>>>(Q, Qbf, rq, NQ);
  norm_bf16_kernel<<<NS / 4, 256, 0, stream>>>(S, Sbf, rs, NS);
  label_init_kernel<<<NS / 256, 256, 0, stream>>>(OH, lab, packedE, packedA, cnt);

  gemm_margin_kernel<<<(NQ / BM) * SSPLIT, 256, 0, stream>>>(Qbf, Sbf, packedA, cand, cnt);

  rescore_kernel<<<1024, 256, 0, stream>>>(Q, S, rq, rs, packedA, cand, cnt, packedE);

  finalize_kernel<<<(NQ * NC) / 256, 256, 0, stream>>>(packedE, lab, out);
}

// Round 10
// 518.823 us; speedup vs baseline: 1.1831x; 1.1831x over previous
//
#include <hip/hip_runtime.h>
#include <stdint.h>

#define NQ 8192
#define NS 16384
#define DIM 512
#define NC 64
#define MARGIN 0.01f
#define CAND_CAP (1 << 20)     // 1M global candidates (16 MB)
#define LCAP 1024              // per-block-tile LDS candidate cap (overflow -> global path)

#define BM 256
#define BN 256
#define BK 64
#define SSPLIT 8
#define SCHUNK (NS / SSPLIT)     // 2048
#define NTILES (SCHUNK / BN)     // 8
#define KSTEPS (DIM / BK)        // 8
#define TOTKS (NTILES * KSTEPS)  // 64 K-steps per block

typedef unsigned short ushort;
typedef __attribute__((ext_vector_type(8))) short bf16x8;
typedef __attribute__((ext_vector_type(4))) float f32x4;

// ---------- helpers ----------
__device__ __forceinline__ uint32_t fkey(float f) {
  uint32_t u = __float_as_uint(f);
  return (u & 0x80000000u) ? ~u : (u | 0x80000000u);
}
__device__ __forceinline__ float unfkey(uint32_t k) {
  return __uint_as_float((k & 0x80000000u) ? (k & 0x7FFFFFFFu) : ~k);
}
__device__ __forceinline__ ushort f2bf_rne(float f) {
  uint32_t u = __float_as_uint(f);
  return (ushort)((u + 0x7fffu + ((u >> 16) & 1u)) >> 16);
}
__device__ __forceinline__ void gload_lds16(const void* g, void* lds) {
  __builtin_amdgcn_global_load_lds(
      (const __attribute__((address_space(1))) uint32_t*)g,
      (__attribute__((address_space(3))) uint32_t*)lds, 16, 0, 0);
}

// ---------- pre-pass: row-normalize -> bf16 + rnorm scale ----------
__global__ void norm_bf16_kernel(const float* __restrict__ X,
                                 ushort* __restrict__ Xbf, float* __restrict__ rX,
                                 int nrows) {
  int w = threadIdx.x >> 6, l = threadIdx.x & 63;
  int row = blockIdx.x * 4 + w;
  if (row >= nrows) return;
  const float4* x = (const float4*)(X + (size_t)row * DIM);
  float4 v0 = x[l], v1 = x[l + 64];
  float s = v0.x*v0.x + v0.y*v0.y + v0.z*v0.z + v0.w*v0.w
          + v1.x*v1.x + v1.y*v1.y + v1.z*v1.z + v1.w*v1.w;
  #pragma unroll
  for (int off = 32; off; off >>= 1) s += __shfl_xor(s, off);
  float r = rsqrtf(fmaxf(s, 1e-12f));
  if (l == 0) rX[row] = r;
  size_t base = (size_t)row * DIM + 4 * l;
  *(ushort4*)&Xbf[base] = make_ushort4(f2bf_rne(v0.x*r), f2bf_rne(v0.y*r),
                                       f2bf_rne(v0.z*r), f2bf_rne(v0.w*r));
  *(ushort4*)&Xbf[base + 256] = make_ushort4(f2bf_rne(v1.x*r), f2bf_rne(v1.y*r),
                                             f2bf_rne(v1.z*r), f2bf_rne(v1.w*r));
}

// labels from one-hot + zero result/candidate state (must re-init every call)
__global__ void label_init_kernel(const float* __restrict__ oh, int* __restrict__ lab,
                                  unsigned long long* __restrict__ packedE,
                                  uint32_t* __restrict__ packedA, int* __restrict__ cnt) {
  int i = blockIdx.x * 256 + threadIdx.x;
  if (i == 0) *cnt = 0;
  if (i < NQ) { packedE[i] = 0ull; packedA[i] = 0u; }
  if (i < NS) {
    const float* row = oh + (size_t)i * NC;
    int l = 0;
    #pragma unroll
    for (int j = 0; j < NC; ++j) l = (row[j] > 0.5f) ? j : l;
    lab[i] = l;
  }
}

// ---------- pass 1: 256x256 bf16 GEMM, R3-parity 2-phase schedule + margin emission ----
// Per K-step (BK=64): P1{12 ds_read, stage A(n+1), bar, 32 MFMA, bar}
//                     P2{12 ds_read, stage B(n+1), bar, 32 MFMA, vmcnt(0), bar}
// 16 MFMA/barrier (R3 parity). 8 waves = 2/SIMD. 128-B rows, ^(row&7): 0 conflicts.
__global__ __launch_bounds__(512, 1) void gemm_margin_kernel(
    const ushort* __restrict__ Qbf, const ushort* __restrict__ Sbf,
    uint32_t* __restrict__ packedA, int4* __restrict__ cand, int* __restrict__ cnt)
{
  __shared__ ushort At[2][BM * BK];    // 64 KB
  __shared__ ushort Bt[2][BN * BK];    // 64 KB
  __shared__ float merged[BM][4];      //  4 KB
  __shared__ float runmax[BM];         //  1 KB
  __shared__ int4 lbuf[LCAP];          // 16 KB
  __shared__ int lcnt, lbase;

  const int tid = threadIdx.x;
  const int w = tid >> 6, l = tid & 63;
  const int wr = w >> 2, wcn = w & 3;           // 2 (M) x 4 (N) wave grid
  const int c = l & 15, g = l >> 4;

  // T1: XCD swizzle (256 blocks). XCD x owns s-chunk x (2 MB, L2-resident) x 32 q-panels.
  const int flat = blockIdx.x;
  const int nf = (flat & 7) * 32 + (flat >> 3);
  const int sbq = nf >> 5, qb = nf & 31;
  const int qbase = qb * BM, sbase = sbq * SCHUNK;

  // staging: one gload16 per wave covers 8 rows x 128 B (8 lanes/row, 16 B each)
  const int lrow = l >> 3;                               // 0..7
  const int lslot = ((l & 7) ^ lrow) * 16;               // pre-swizzled src granule
  const char* srcA0 = (const char*)Qbf + (size_t)(qbase + w * 8 + lrow) * 1024 + lslot;
  const char* srcB0 = (const char*)Sbf + (size_t)(sbase + w * 8 + lrow) * 1024 + lslot;
  const int ldst0 = (w * 8) * 128;                       // wave-uniform dest (bytes)

  // u in 0..3 covers rows u*64 .. u*64+63 (8 rows per wave each); 4 gloads = full tile
  #define STAGE_A(buf, n) do {                                                    \
    const size_t kb_ = (size_t)((n) & 7) * 128;                                   \
    _Pragma("unroll")                                                             \
    for (int u_ = 0; u_ < 4; ++u_)                                                \
      gload_lds16(srcA0 + (size_t)u_ * 65536 + kb_,                               \
                  (char*)&At[(buf)][0] + ldst0 + u_ * 8192);                      \
  } while (0)
  #define STAGE_B(buf, n) do {                                                    \
    const size_t ob_ = (size_t)((n) >> 3) * 262144 + (size_t)((n) & 7) * 128;     \
    _Pragma("unroll")                                                             \
    for (int u_ = 0; u_ < 4; ++u_)                                                \
      gload_lds16(srcB0 + ob_ + (size_t)u_ * 65536,                               \
                  (char*)&Bt[(buf)][0] + ldst0 + u_ * 8192);                      \
  } while (0)

  // fragment read bases (bytes); frag rows = base16 + c so row&7 == c&7
  const int aoff = (wr * 128 + c) * 128;
  const int boff = (wcn * 64 + c) * 128;
  const int s0 = ((g) ^ (c & 7)) * 16;          // k 0-31 granule
  const int s1 = ((4 + g) ^ (c & 7)) * 16;      // k 32-63 granule

  float rm = -2.0f;                              // running chunk max (tid < 256)
  if (tid == 0) lcnt = 0;

  // prologue: stage K-step 0 into buf 0 (8 gloads/thread); full drain
  STAGE_A(0, 0);
  STAGE_B(0, 0);
  __syncthreads();   // compiler drains vmcnt+lgkm before barrier

  for (int t = 0; t < NTILES; ++t) {
    f32x4 acc[8][4];
    #pragma unroll
    for (int m = 0; m < 8; ++m)
      #pragma unroll
      for (int n = 0; n < 4; ++n) acc[m][n] = (f32x4)0.0f;

    for (int k = 0; k < KSTEPS; ++k) {
      const int n = t * KSTEPS + k;
      const int cur = n & 1, nxt = cur ^ 1;
      const bool pf = (n + 1 < TOTKS);
      const char* Ac = (const char*)&At[cur][0];
      const char* Bc = (const char*)&Bt[cur][0];
      bf16x8 a[8], b[4];

      // ---- P1: k 0-31 ----
      #pragma unroll
      for (int m = 0; m < 8; ++m) a[m] = *(const bf16x8*)(Ac + aoff + m * 2048 + s0);
      #pragma unroll
      for (int j = 0; j < 4; ++j) b[j] = *(const bf16x8*)(Bc + boff + j * 2048 + s0);
      if (pf) STAGE_A(nxt, n + 1);
      __builtin_amdgcn_s_barrier();              // phase-lock waves (reads already dep-ordered)
      __builtin_amdgcn_s_setprio(1);
      #pragma unroll
      for (int m = 0; m < 8; ++m)
        #pragma unroll
        for (int j = 0; j < 4; ++j)
          acc[m][j] = __builtin_amdgcn_mfma_f32_16x16x32_bf16(a[m], b[j], acc[m][j], 0, 0, 0);
      __builtin_amdgcn_s_setprio(0);
      __builtin_amdgcn_s_barrier();

      // ---- P2: k 32-63 ----
      #pragma unroll
      for (int m = 0; m < 8; ++m) a[m] = *(const bf16x8*)(Ac + aoff + m * 2048 + s1);
      #pragma unroll
      for (int j = 0; j < 4; ++j) b[j] = *(const bf16x8*)(Bc + boff + j * 2048 + s1);
      if (pf) STAGE_B(nxt, n + 1);
      __builtin_amdgcn_s_barrier();
      __builtin_amdgcn_s_setprio(1);
      #pragma unroll
      for (int m = 0; m < 8; ++m)
        #pragma unroll
        for (int j = 0; j < 4; ++j)
          acc[m][j] = __builtin_amdgcn_mfma_f32_16x16x32_bf16(a[m], b[j], acc[m][j], 0, 0, 0);
      __builtin_amdgcn_s_setprio(0);
      // end-of-step: own 8 staging loads landed; raw barrier -> all waves' writes visible
      asm volatile("s_waitcnt vmcnt(0)" ::: "memory");
      __builtin_amdgcn_s_barrier();
    }

    // ---- epilogue: rowmax merge -> runmax -> two-level candidate emission ----
    // C/D: col = wcn*64 + j*16 + c ; row = wr*128 + m*16 + g*4 + r
    #pragma unroll
    for (int m = 0; m < 8; ++m)
      #pragma unroll
      for (int r = 0; r < 4; ++r) {
        float v = acc[m][0][r];
        #pragma unroll
        for (int j = 1; j < 4; ++j) v = fmaxf(v, acc[m][j][r]);
        #pragma unroll
        for (int off = 1; off < 16; off <<= 1) v = fmaxf(v, __shfl_xor(v, off));
        if (c == 0) merged[wr * 128 + m * 16 + g * 4 + r][wcn] = v;
      }
    __syncthreads();
    if (tid < BM) {
      float tmax = fmaxf(fmaxf(merged[tid][0], merged[tid][1]),
                         fmaxf(merged[tid][2], merged[tid][3]));
      rm = fmaxf(rm, tmax);
      runmax[tid] = rm;
    }
    __syncthreads();
    {
      const int sb = sbase + t * BN + wcn * 64 + c;
      #pragma unroll
      for (int m = 0; m < 8; ++m)
        #pragma unroll
        for (int r = 0; r < 4; ++r) {
          const int row = wr * 128 + m * 16 + g * 4 + r;
          const float thr = runmax[row] - MARGIN;
          #pragma unroll
          for (int j = 0; j < 4; ++j) {
            float v = acc[m][j][r];
            if (v >= thr) {
              int s = atomicAdd(&lcnt, 1);     // LDS atomic: block-local
              if (s < LCAP) lbuf[s] = make_int4(qbase + row, sb + j * 16, __float_as_int(v), 0);
              else {                            // overflow: direct global (correctness)
                int gi = atomicAdd(cnt, 1);
                if (gi < CAND_CAP) cand[gi] = make_int4(qbase + row, sb + j * 16, __float_as_int(v), 0);
              }
            }
          }
        }
    }
    __syncthreads();
    if (tid == 0) {                             // ONE global atomic per block-tile
      int take = lcnt < LCAP ? lcnt : LCAP;
      lbase = atomicAdd(cnt, take);
      lcnt = take;
    }
    __syncthreads();
    for (int i = tid; i < lcnt; i += 512) {
      int gi = lbase + i;
      if (gi < CAND_CAP) cand[gi] = lbuf[i];
    }
    __syncthreads();
    if (tid == 0) lcnt = 0;
    __syncthreads();   // reset visible before next tile's emission
  }

  if (tid < BM) atomicMax(&packedA[qbase + tid], fkey(rm));

  #undef STAGE_A
  #undef STAGE_B
}

// ---------- pass 2: exact fp32 rescore of filtered candidates ----------
__global__ void rescore_kernel(const float* __restrict__ Q, const float* __restrict__ S,
                               const float* __restrict__ rq, const float* __restrict__ rs,
                               const uint32_t* __restrict__ packedA,
                               const int4* __restrict__ cand, const int* __restrict__ cnt,
                               unsigned long long* __restrict__ packedE) {
  const int nw = (gridDim.x * blockDim.x) >> 6;
  const int wid = (blockIdx.x * blockDim.x + threadIdx.x) >> 6;
  const int l = threadIdx.x & 63;
  int n = *cnt; if (n > CAND_CAP) n = CAND_CAP;
  for (int ci = wid; ci < n; ci += nw) {
    int4 cd = cand[ci];
    float maxA = unfkey(packedA[cd.x]);
    float apx = __int_as_float(cd.z);
    if (apx < maxA - MARGIN) continue;     // provably not the winner
    const float4* qp = (const float4*)(Q + (size_t)cd.x * DIM);
    const float4* sp = (const float4*)(S + (size_t)cd.y * DIM);
    float4 a0 = qp[l], b0 = sp[l], a1 = qp[l + 64], b1 = sp[l + 64];
    float d = a0.x*b0.x + a0.y*b0.y + a0.z*b0.z + a0.w*b0.w
            + a1.x*b1.x + a1.y*b1.y + a1.z*b1.z + a1.w*b1.w;
    #pragma unroll
    for (int off = 32; off; off >>= 1) d += __shfl_xor(d, off);
    if (l == 0) {
      float ex = d * rq[cd.x] * rs[cd.y];
      unsigned long long p =
          ((unsigned long long)fkey(ex) << 32) | (uint32_t)(~(uint32_t)cd.y);
      atomicMax(&packedE[cd.x], p);
    }
  }
}

__global__ void finalize_kernel(const unsigned long long* __restrict__ packedE,
                                const int* __restrict__ lab, float* __restrict__ out) {
  int gid = blockIdx.x * 256 + threadIdx.x;
  if (gid >= NQ * NC) return;
  int q = gid >> 6, cl = gid & 63;
  unsigned long long p = packedE[q];
  if (p == 0ull) { out[gid] = 0.0f; return; }   // safety: never expected
  uint32_t n = ~(uint32_t)p;
  float v = unfkey((uint32_t)(p >> 32));
  out[gid] = (cl == lab[n]) ? v : 0.0f;
}

// ---------- launch ----------
extern "C" void kernel_launch(void* const* d_in, const int* in_sizes, int n_in,
                              void* d_out, int out_size, void* d_ws, size_t ws_size,
                              hipStream_t stream) {
  const float* Q  = (const float*)d_in[0];   // [8192, 512]
  const float* S  = (const float*)d_in[1];   // [16384, 512]
  const float* OH = (const float*)d_in[2];   // [16384, 64]
  float* out = (float*)d_out;                // [8192, 64]

  char* ws = (char*)d_ws;
  int* lab                    = (int*)(ws);                             //  64 KB
  unsigned long long* packedE = (unsigned long long*)(ws + (1 << 16));  //  64 KB
  uint32_t* packedA           = (uint32_t*)(ws + (2 << 16));            //  32 KB
  int* cnt                    = (int*)(ws + (3 << 16));                 //   4 KB
  float* rq                   = (float*)(ws + 200704);                  //  32 KB
  float* rs                   = (float*)(ws + 233472);                  //  64 KB
  ushort* Qbf                 = (ushort*)(ws + 299008);                 //   8 MB
  ushort* Sbf                 = (ushort*)(ws + 299008 + 8388608);       //  16 MB
  int4* cand                  = (int4*)(ws + 299008 + 8388608 + 16777216); // 16 MB

  norm_bf16_kernel<<<NQ / 4, 256, 0, stream>>>(Q, Qbf, rq, NQ);
  norm_bf16_kernel<<<NS / 4, 256, 0, stream>>>(S, Sbf, rs, NS);
  label_init_kernel<<<NS / 256, 256, 0, stream>>>(OH, lab, packedE, packedA, cnt);

  gemm_margin_kernel<<<(NQ / BM) * SSPLIT, 512, 0, stream>>>(Qbf, Sbf, packedA, cand, cnt);

  rescore_kernel<<<1024, 256, 0, stream>>>(Q, S, rq, rs, packedA, cand, cnt, packedE);

  finalize_kernel<<<(NQ * NC) / 256, 256, 0, stream>>>(packedE, lab, out);
}

// Round 11
// 297.491 us; speedup vs baseline: 2.0633x; 1.7440x over previous
//
#include <hip/hip_runtime.h>
#include <stdint.h>

#define NQ 8192
#define NS 16384
#define DIM 512
#define NC 64
#define MARGIN 0.01f
#define CAND_CAP (1 << 20)     // 1M global candidates (16 MB)
#define LCAP 512               // per-block-tile LDS candidate cap (overflow -> global path)

typedef unsigned short ushort;
typedef __attribute__((ext_vector_type(8))) short bf16x8;
typedef __attribute__((ext_vector_type(4))) float f32x4;

// ---------- helpers ----------
__device__ __forceinline__ uint32_t fkey(float f) {
  uint32_t u = __float_as_uint(f);
  return (u & 0x80000000u) ? ~u : (u | 0x80000000u);
}
__device__ __forceinline__ float unfkey(uint32_t k) {
  return __uint_as_float((k & 0x80000000u) ? (k & 0x7FFFFFFFu) : ~k);
}
__device__ __forceinline__ ushort f2bf_rne(float f) {
  uint32_t u = __float_as_uint(f);
  return (ushort)((u + 0x7fffu + ((u >> 16) & 1u)) >> 16);
}
__device__ __forceinline__ void gload_lds16(const void* g, void* lds) {
  __builtin_amdgcn_global_load_lds(
      (const __attribute__((address_space(1))) uint32_t*)g,
      (__attribute__((address_space(3))) uint32_t*)lds, 16, 0, 0);
}

// ---------- pre-pass: row-normalize -> bf16 + rnorm scale ----------
__global__ void norm_bf16_kernel(const float* __restrict__ X,
                                 ushort* __restrict__ Xbf, float* __restrict__ rX,
                                 int nrows) {
  int w = threadIdx.x >> 6, l = threadIdx.x & 63;
  int row = blockIdx.x * 4 + w;
  if (row >= nrows) return;
  const float4* x = (const float4*)(X + (size_t)row * DIM);
  float4 v0 = x[l], v1 = x[l + 64];
  float s = v0.x*v0.x + v0.y*v0.y + v0.z*v0.z + v0.w*v0.w
          + v1.x*v1.x + v1.y*v1.y + v1.z*v1.z + v1.w*v1.w;
  #pragma unroll
  for (int off = 32; off; off >>= 1) s += __shfl_xor(s, off);
  float r = rsqrtf(fmaxf(s, 1e-12f));
  if (l == 0) rX[row] = r;
  size_t base = (size_t)row * DIM + 4 * l;
  *(ushort4*)&Xbf[base] = make_ushort4(f2bf_rne(v0.x*r), f2bf_rne(v0.y*r),
                                       f2bf_rne(v0.z*r), f2bf_rne(v0.w*r));
  *(ushort4*)&Xbf[base + 256] = make_ushort4(f2bf_rne(v1.x*r), f2bf_rne(v1.y*r),
                                             f2bf_rne(v1.z*r), f2bf_rne(v1.w*r));
}

// labels from one-hot + zero result/candidate state (must re-init every call)
__global__ void label_init_kernel(const float* __restrict__ oh, int* __restrict__ lab,
                                  unsigned long long* __restrict__ packedE,
                                  uint32_t* __restrict__ packedA, int* __restrict__ cnt) {
  int i = blockIdx.x * 256 + threadIdx.x;
  if (i == 0) *cnt = 0;
  if (i < NQ) { packedE[i] = 0ull; packedA[i] = 0u; }
  if (i < NS) {
    const float* row = oh + (size_t)i * NC;
    int l = 0;
    #pragma unroll
    for (int j = 0; j < NC; ++j) l = (row[j] > 0.5f) ? j : l;
    lab[i] = l;
  }
}

// ---------- pass 1: R5 GEMM (128x256, BK=64) + ring-of-3 counted-vmcnt staging ----------
// R5 verbatim except: 3 LDS buffers, prologue stages steps 0+1, step n issues
// stage(n+2), end-of-step vmcnt(6) keeps the newest stage in flight (T4).
__global__ __launch_bounds__(512, 2) void gemm_margin_kernel(
    const ushort* __restrict__ Qbf, const ushort* __restrict__ Sbf,
    uint32_t* __restrict__ packedA, int4* __restrict__ cand, int* __restrict__ cnt)
{
  // ring of 3: A 128x64 (16 KB) + B 256x64 (32 KB) each; 144 KB total.
  // 128 B rows; phys 16B-granule p holds logical p ^ (row & 7)  [verified 0-conflict]
  __shared__ ushort Atile[3][128 * 64];
  __shared__ ushort Btile[3][256 * 64];
  __shared__ float merged[128][4];
  __shared__ float runmax[128];
  __shared__ int4 lbuf[LCAP];           // 8 KB
  __shared__ int lcnt, lbase;

  const int tid = threadIdx.x;
  const int w = tid >> 6, l = tid & 63;
  const int wr = w >> 2, wcn = w & 3;           // 2 (M) x 4 (N) wave grid
  const int c = l & 15, g = l >> 4;

  // T1: XCD swizzle (1024 blocks, bijective)
  const int flat = blockIdx.x;
  const int nf = (flat & 7) * 128 + (flat >> 3);
  const int sbq = nf >> 6, qb = nf & 63;        // 16 s-chunks x 64 q-blocks
  const int qbase = qb * 128, sbase = sbq * 1024;

  // staging: per instr one wave covers 8 rows x 128 B; pre-swizzled source slot.
  const int lrow = l >> 3;
  const size_t lslot = (size_t)(((l & 7) ^ lrow) * 16);   // bytes
  const char* srcA = (const char*)Qbf + (size_t)(qbase + w * 8 + lrow) * 1024 + lslot;
  const char* srcB = (const char*)Sbf + (size_t)(sbase + w * 8 + lrow) * 1024 + lslot;
  const int ldst = (w * 8) * 128;               // wave-uniform byte offset

  // TOTKS = 32 steps (4 B-tiles x 8 K-steps). A: 2 gloads/thread, B: 4.
  #define STAGE_A(buf, n) do { const size_t kb_ = (size_t)((n) & 7) * 128;          \
    gload_lds16(srcA + kb_,         (char*)&Atile[(buf)][0] + ldst);                \
    gload_lds16(srcA + kb_ + 65536, (char*)&Atile[(buf)][0] + ldst + 8192);         \
  } while (0)
  #define STAGE_B(buf, n) do {                                                      \
    const size_t ob_ = (size_t)((n) >> 3) * 262144 + (size_t)((n) & 7) * 128;       \
    gload_lds16(srcB + ob_,          (char*)&Btile[(buf)][0] + ldst);               \
    gload_lds16(srcB + ob_ +  65536, (char*)&Btile[(buf)][0] + ldst +  8192);       \
    gload_lds16(srcB + ob_ + 131072, (char*)&Btile[(buf)][0] + ldst + 16384);       \
    gload_lds16(srcB + ob_ + 196608, (char*)&Btile[(buf)][0] + ldst + 24576);       \
  } while (0)

  // fragment read bases (bytes): row*128 + (slice ^ (c&7))*16
  const int arow = (wr * 64 + c) * 128;
  const int brow = (wcn * 64 + c) * 128;
  const int sl0 = ((g) ^ (c & 7)) * 16;
  const int sl1 = ((4 + g) ^ (c & 7)) * 16;

  float rm = -2.0f;   // running chunk max for query row tid (tid < 128)
  if (tid == 0) lcnt = 0;

  // prologue: stage steps 0 and 1; wait only for step 0 (all but newest 6)
  STAGE_A(0, 0); STAGE_B(0, 0);
  STAGE_A(1, 1); STAGE_B(1, 1);
  asm volatile("s_waitcnt vmcnt(6)" ::: "memory");
  __builtin_amdgcn_s_barrier();

  for (int t = 0; t < 4; ++t) {
    f32x4 acc[4][4];
    #pragma unroll
    for (int m = 0; m < 4; ++m)
      #pragma unroll
      for (int n = 0; n < 4; ++n) acc[m][n] = (f32x4)0.0f;

    for (int k8 = 0; k8 < 8; ++k8) {
      const int n = t * 8 + k8;
      const int cur = n % 3;
      const int pre = (n + 2) % 3;
      const bool pf = (n + 2 < 32);
      const char* At = (const char*)&Atile[cur][0];
      const char* Bt = (const char*)&Btile[cur][0];
      bf16x8 ah[4], bh[4];

      // ---- P1: k-slices 0-3; prefetch A(n+2) ----
      #pragma unroll
      for (int m = 0; m < 4; ++m) ah[m] = *(const bf16x8*)(At + arow + m * 16 * 128 + sl0);
      #pragma unroll
      for (int j = 0; j < 4; ++j) bh[j] = *(const bf16x8*)(Bt + brow + j * 16 * 128 + sl0);
      if (pf) STAGE_A(pre, n + 2);
      asm volatile("s_waitcnt lgkmcnt(0)" ::: "memory");
      __builtin_amdgcn_s_setprio(1);
      #pragma unroll
      for (int m = 0; m < 4; ++m)
        #pragma unroll
        for (int j = 0; j < 4; ++j)
          acc[m][j] = __builtin_amdgcn_mfma_f32_16x16x32_bf16(ah[m], bh[j], acc[m][j], 0, 0, 0);
      __builtin_amdgcn_s_setprio(0);

      // ---- P2: k-slices 4-7; prefetch B(n+2) ----
      #pragma unroll
      for (int m = 0; m < 4; ++m) ah[m] = *(const bf16x8*)(At + arow + m * 16 * 128 + sl1);
      #pragma unroll
      for (int j = 0; j < 4; ++j) bh[j] = *(const bf16x8*)(Bt + brow + j * 16 * 128 + sl1);
      if (pf) STAGE_B(pre, n + 2);
      asm volatile("s_waitcnt lgkmcnt(0)" ::: "memory");
      __builtin_amdgcn_s_setprio(1);
      #pragma unroll
      for (int m = 0; m < 4; ++m)
        #pragma unroll
        for (int j = 0; j < 4; ++j)
          acc[m][j] = __builtin_amdgcn_mfma_f32_16x16x32_bf16(ah[m], bh[j], acc[m][j], 0, 0, 0);
      __builtin_amdgcn_s_setprio(0);

      // ---- counted end-of-step drain: stage(n+1) done, stage(n+2) in flight ----
      if (pf) asm volatile("s_waitcnt vmcnt(6)" ::: "memory");
      else    asm volatile("s_waitcnt vmcnt(0)" ::: "memory");
      __builtin_amdgcn_s_barrier();
    }

    // ---- epilogue: rowmax merge -> runmax -> two-level candidate emission ----
    // C/D: col = wcn*64 + j*16 + c ; row = wr*64 + m*16 + g*4 + r
    #pragma unroll
    for (int m = 0; m < 4; ++m)
      #pragma unroll
      for (int r = 0; r < 4; ++r) {
        float v = acc[m][0][r];
        #pragma unroll
        for (int j = 1; j < 4; ++j) v = fmaxf(v, acc[m][j][r]);
        #pragma unroll
        for (int off = 1; off < 16; off <<= 1) v = fmaxf(v, __shfl_xor(v, off));
        if (c == 0) merged[wr * 64 + m * 16 + g * 4 + r][wcn] = v;
      }
    __syncthreads();
    if (tid < 128) {
      float tmax = fmaxf(fmaxf(merged[tid][0], merged[tid][1]),
                         fmaxf(merged[tid][2], merged[tid][3]));
      rm = fmaxf(rm, tmax);
      runmax[tid] = rm;
    }
    __syncthreads();
    {
      const int sb = sbase + t * 256 + wcn * 64 + c;
      #pragma unroll
      for (int m = 0; m < 4; ++m)
        #pragma unroll
        for (int r = 0; r < 4; ++r) {
          const int row = wr * 64 + m * 16 + g * 4 + r;
          const float thr = runmax[row] - MARGIN;
          #pragma unroll
          for (int j = 0; j < 4; ++j) {
            float v = acc[m][j][r];
            if (v >= thr) {
              int s = atomicAdd(&lcnt, 1);     // LDS atomic: block-local
              if (s < LCAP) lbuf[s] = make_int4(qbase + row, sb + j * 16, __float_as_int(v), 0);
              else {                            // overflow: direct global (correctness)
                int gi = atomicAdd(cnt, 1);
                if (gi < CAND_CAP) cand[gi] = make_int4(qbase + row, sb + j * 16, __float_as_int(v), 0);
              }
            }
          }
        }
    }
    __syncthreads();
    if (tid == 0) {                             // ONE global atomic per block-tile
      int take = lcnt < LCAP ? lcnt : LCAP;
      lbase = atomicAdd(cnt, take);
      lcnt = take;
    }
    __syncthreads();
    for (int i = tid; i < lcnt; i += 512) {
      int gi = lbase + i;
      if (gi < CAND_CAP) cand[gi] = lbuf[i];
    }
    __syncthreads();
    if (tid == 0) lcnt = 0;
    __syncthreads();   // reset visible before next tile's emission
  }

  if (tid < 128) atomicMax(&packedA[qbase + tid], fkey(rm));

  #undef STAGE_A
  #undef STAGE_B
}

// ---------- pass 2: exact fp32 rescore of filtered candidates ----------
__global__ void rescore_kernel(const float* __restrict__ Q, const float* __restrict__ S,
                               const float* __restrict__ rq, const float* __restrict__ rs,
                               const uint32_t* __restrict__ packedA,
                               const int4* __restrict__ cand, const int* __restrict__ cnt,
                               unsigned long long* __restrict__ packedE) {
  const int nw = (gridDim.x * blockDim.x) >> 6;
  const int wid = (blockIdx.x * blockDim.x + threadIdx.x) >> 6;
  const int l = threadIdx.x & 63;
  int n = *cnt; if (n > CAND_CAP) n = CAND_CAP;
  for (int ci = wid; ci < n; ci += nw) {
    int4 cd = cand[ci];
    float maxA = unfkey(packedA[cd.x]);
    float apx = __int_as_float(cd.z);
    if (apx < maxA - MARGIN) continue;     // provably not the winner
    const float4* qp = (const float4*)(Q + (size_t)cd.x * DIM);
    const float4* sp = (const float4*)(S + (size_t)cd.y * DIM);
    float4 a0 = qp[l], b0 = sp[l], a1 = qp[l + 64], b1 = sp[l + 64];
    float d = a0.x*b0.x + a0.y*b0.y + a0.z*b0.z + a0.w*b0.w
            + a1.x*b1.x + a1.y*b1.y + a1.z*b1.z + a1.w*b1.w;
    #pragma unroll
    for (int off = 32; off; off >>= 1) d += __shfl_xor(d, off);
    if (l == 0) {
      float ex = d * rq[cd.x] * rs[cd.y];
      unsigned long long p =
          ((unsigned long long)fkey(ex) << 32) | (uint32_t)(~(uint32_t)cd.y);
      atomicMax(&packedE[cd.x], p);
    }
  }
}

__global__ void finalize_kernel(const unsigned long long* __restrict__ packedE,
                                const int* __restrict__ lab, float* __restrict__ out) {
  int gid = blockIdx.x * 256 + threadIdx.x;
  if (gid >= NQ * NC) return;
  int q = gid >> 6, cl = gid & 63;
  unsigned long long p = packedE[q];
  if (p == 0ull) { out[gid] = 0.0f; return; }   // safety: never expected
  uint32_t n = ~(uint32_t)p;
  float v = unfkey((uint32_t)(p >> 32));
  out[gid] = (cl == lab[n]) ? v : 0.0f;
}

// ---------- launch ----------
extern "C" void kernel_launch(void* const* d_in, const int* in_sizes, int n_in,
                              void* d_out, int out_size, void* d_ws, size_t ws_size,
                              hipStream_t stream) {
  const float* Q  = (const float*)d_in[0];   // [8192, 512]
  const float* S  = (const float*)d_in[1];   // [16384, 512]
  const float* OH = (const float*)d_in[2];   // [16384, 64]
  float* out = (float*)d_out;                // [8192, 64]

  char* ws = (char*)d_ws;
  int* lab                    = (int*)(ws);                             //  64 KB
  unsigned long long* packedE = (unsigned long long*)(ws + (1 << 16));  //  64 KB
  uint32_t* packedA           = (uint32_t*)(ws + (2 << 16));            //  32 KB
  int* cnt                    = (int*)(ws + (3 << 16));                 //   4 KB
  float* rq                   = (float*)(ws + 200704);                  //  32 KB
  float* rs                   = (float*)(ws + 233472);                  //  64 KB
  ushort* Qbf                 = (ushort*)(ws + 299008);                 //   8 MB
  ushort* Sbf                 = (ushort*)(ws + 299008 + 8388608);       //  16 MB
  int4* cand                  = (int4*)(ws + 299008 + 8388608 + 16777216); // 16 MB

  norm_bf16_kernel<<<NQ / 4, 256, 0, stream>>>(Q, Qbf, rq, NQ);
  norm_bf16_kernel<<<NS / 4, 256, 0, stream>>>(S, Sbf, rs, NS);
  label_init_kernel<<<NS / 256, 256, 0, stream>>>(OH, lab, packedE, packedA, cnt);

  gemm_margin_kernel<<<1024, 512, 0, stream>>>(Qbf, Sbf, packedA, cand, cnt);

  rescore_kernel<<<2048, 256, 0, stream>>>(Q, S, rq, rs, packedA, cand, cnt, packedE);

  finalize_kernel<<<(NQ * NC) / 256, 256, 0, stream>>>(packedE, lab, out);
}